// Round 14
// baseline (17.156 us; speedup 1.0000x reference)
//
#include <hip/hip_runtime.h>
#include <math.h>

#define BB 2
#define C_IN 32
#define HH 64
#define WW 64
#define J (HH*WW)        // 4096
#define HID 64
#define C_OUT 32
#define S 256
#define CSTR 12          // coef row stride (floats)

// gelu(x) ~= x * sigmoid(A*x + B*x^3)  (tanh-form gelu, exp2 domain)
#define GELU_A 2.3022043f
#define GELU_B 0.10294306f

// ---------- kernel 1: per (b,h): u recompute -> F at 4 Chebyshev nodes ----------
// -> cubic fit in t -> expand to 10 monomial coefs in (x,y), scaled by 1/S.
__global__ __launch_bounds__(256) void k_coef(
    const float* __restrict__ v, const int* __restrict__ indices,
    const float* __restrict__ W1, const float* __restrict__ b1,
    float* __restrict__ coefG)
{
    __shared__ float us[4 * 66];         // u[b,:,h], 4 padded s-quarters
    __shared__ float Fsh[4];
    int tid = threadIdx.x;
    int blk = blockIdx.x;                // 0..127
    int b   = blk >> 6;
    int h   = blk & 63;

    float w0 = W1[h], w1 = W1[HID + h];  // block-uniform

    // --- phase A (R13-proven): u[b,s,h] for s = tid ---
    {
        int s   = tid;
        int idx = indices[s];
        float sx = (float)(idx & (WW - 1)) * (1.0f / (WW - 1));
        float sy = (float)(idx >> 6)       * (1.0f / (HH - 1));
        float acc = b1[h] - sx * w0 - sy * w1;
        const float* vb = v + (size_t)b * C_IN * J + idx;
        #pragma unroll
        for (int c = 0; c < C_IN; ++c) {
            acc = __builtin_fmaf(vb[c * J], W1[(2 + c) * HID + h], acc);
        }
        us[(s >> 6) * 66 + (s & 63)] = acc;
    }
    __syncthreads();

    float c0  = fminf(w0, 0.0f) + fminf(w1, 0.0f);
    float c1  = fmaxf(w0, 0.0f) + fmaxf(w1, 0.0f);
    float mid = 0.5f * (c0 + c1);
    float R   = 0.5f * fmaxf(c1 - c0, 1e-6f);

    // --- phase B: wave k sums gelu at node k; lane l covers s = l + 64q ---
    int k = tid >> 6;                    // node index 0..3 (wave id)
    int l = tid & 63;
    float tk = (k == 0) ?  0.9238795f :
               (k == 1) ?  0.3826834f :
               (k == 2) ? -0.3826834f : -0.9238795f;   // static select, no scratch
    float cn = __builtin_fmaf(R, tk, mid);

    float acc = 0.0f;
    #pragma unroll
    for (int q = 0; q < 4; ++q) {
        float x = cn + us[q * 66 + l];
        float p = __builtin_fmaf(-GELU_B, x * x, -GELU_A);
        float e = __builtin_amdgcn_exp2f(p * x);
        acc = __builtin_fmaf(x, __builtin_amdgcn_rcpf(e + 1.0f), acc);
    }
    acc += __shfl_xor(acc, 1);
    acc += __shfl_xor(acc, 2);
    acc += __shfl_xor(acc, 4);
    acc += __shfl_xor(acc, 8);
    acc += __shfl_xor(acc, 16);
    acc += __shfl_xor(acc, 32);
    if (l == 0) Fsh[k] = acc;
    __syncthreads();

    // --- phase C: cubic fit (inverse Vandermonde at Chebyshev nodes,
    //     verified on t/t^2/t^3 basis) + monomial expansion ---
    if (tid == 0) {
        float F0 = Fsh[0], F1 = Fsh[1], F2 = Fsh[2], F3 = Fsh[3];
        float E0 = 0.5f * (F0 + F3), E1 = 0.5f * (F1 + F2);
        float O0 = 0.5f * (F0 - F3), O1 = 0.5f * (F1 - F2);
        float a2 = 1.4142136f * (E0 - E1);
        float a0 = E1 - 0.14644661f * a2;
        float a1 = -0.2241608f * O0 + 3.1543214f * O1;
        float a3 =  1.5307337f * O0 - 3.6955181f * O1;
        a0 *= (1.0f / S); a1 *= (1.0f / S); a2 *= (1.0f / S); a3 *= (1.0f / S);

        float al = w0 / R, be = w1 / R, ga = -mid / R;   // t = al*x + be*y + ga
        float q1 = a1 + 2.0f * a2 * ga + 3.0f * a3 * ga * ga;
        float q2 = a2 + 3.0f * a3 * ga;
        float* cf = coefG + (size_t)(b * HID + h) * CSTR;
        cf[0] = a0 + ga * (a1 + ga * (a2 + ga * a3));    // 1
        cf[1] = al * q1;                                  // x
        cf[2] = be * q1;                                  // y
        cf[3] = al * al * q2;                             // x^2
        cf[4] = 2.0f * al * be * q2;                      // xy
        cf[5] = be * be * q2;                             // y^2
        cf[6] = a3 * al * al * al;                        // x^3
        cf[7] = 3.0f * a3 * al * al * be;                 // x^2 y
        cf[8] = 3.0f * a3 * al * be * be;                 // x y^2
        cf[9] = a3 * be * be * be;                        // y^3
        cf[10] = 0.0f; cf[11] = 0.0f;
    }
}

// ---------- kernel 2: M = W2^T . coef, then render 10-term polynomial ----------
__global__ __launch_bounds__(256) void k_render(
    const float* __restrict__ coefG, const float* __restrict__ W2,
    const float* __restrict__ b2, float* __restrict__ out)
{
    __shared__ float cl[HID * CSTR];     // 768 floats
    __shared__ float Ml[C_OUT][CSTR];    // 32 x 12
    int tid = threadIdx.x;
    int blk = blockIdx.x;                // 0..255
    int b   = blk >> 7;
    int jt  = blk & 127;                 // 32-j tile (row-contiguous)

    #pragma unroll
    for (int i = 0; i < 3; ++i)
        cl[i * 256 + tid] = coefG[(size_t)b * HID * CSTR + i * 256 + tid];
    __syncthreads();

    // M[co][m] = sum_h W2[h,co] * cl[h][m]
    {
        int co = tid & 31;
        int mg = tid >> 5;               // 0..7; mg<2 also covers m=8,9
        float acc = 0.0f, acc2 = 0.0f;
        #pragma unroll
        for (int h = 0; h < HID; ++h) {
            float w = W2[h * C_OUT + co];
            acc = __builtin_fmaf(w, cl[h * CSTR + mg], acc);
            if (mg < 2) acc2 = __builtin_fmaf(w, cl[h * CSTR + mg + 8], acc2);
        }
        Ml[co][mg] = acc;
        if (mg < 2) Ml[co][mg + 8] = acc2;
    }
    __syncthreads();

    // render: lanes vary jl -> coalesced stores; 4 co per thread
    int jl = tid & 31;
    int cq = tid >> 5;                   // 0..7
    float x = (float)((jt & 1) * 32 + jl) * (1.0f / 63.0f);
    float y = (float)(jt >> 1)            * (1.0f / 63.0f);
    float x2 = x * x, y2 = y * y, xy = x * y;
    float x3 = x2 * x, y3 = y2 * y, x2y = x2 * y, xy2 = x * y2;
    int j0 = jt * 32;
    #pragma unroll
    for (int q = 0; q < 4; ++q) {
        int co = cq + 8 * q;
        const float* M = Ml[co];
        float s = M[0]
                + M[1] * x   + M[2] * y
                + M[3] * x2  + M[4] * xy  + M[5] * y2
                + M[6] * x3  + M[7] * x2y + M[8] * xy2 + M[9] * y3
                + b2[co];
        out[(size_t)b * C_OUT * J + (size_t)co * J + j0 + jl] = s;
    }
}

extern "C" void kernel_launch(void* const* d_in, const int* in_sizes, int n_in,
                              void* d_out, int out_size, void* d_ws, size_t ws_size,
                              hipStream_t stream) {
    const float* v       = (const float*)d_in[0];
    const int*   indices = (const int*)  d_in[1];
    const float* W1      = (const float*)d_in[2];
    const float* b1      = (const float*)d_in[3];
    const float* W2      = (const float*)d_in[4];
    const float* b2      = (const float*)d_in[5];
    float* out   = (float*)d_out;
    float* coefG = (float*)d_ws;         // B*HID*CSTR*4 = 6 KB

    hipLaunchKernelGGL(k_coef,   dim3(BB * HID), dim3(256), 0, stream,
                       v, indices, W1, b1, coefG);
    hipLaunchKernelGGL(k_render, dim3(256),      dim3(256), 0, stream,
                       coefG, W2, b2, out);
}